// Round 5
// baseline (6585.009 us; speedup 1.0000x reference)
//
#include <hip/hip_runtime.h>

// ws layout (floats)
#define WS_GX   0                       // 4096: Gx[cp][c] = alpha*sum_o wk[o][c]*wq[o][cp]
#define WS_CPV  4096                    // 4096: Cpvx[c][o] = sum_m wp[o][m]*wv[m][c]
#define WS_QB   8192                    // 64:   alpha * Wk^T bq
#define WS_BPV  8256                    // 64:   Wp bv + bp
#define WS_C2   8448                    // 4096*1536 conv2 output (flattened fc input)
#define WS_Z1   (8448 + 4096*1536)      // 4096*768 fc1 output

// bf16 helpers: store round-to-nearest-even, load = shift/mask (1 VALU per value)
__device__ __forceinline__ unsigned short f2b(float f) {
  unsigned u = __float_as_uint(f);
  return (unsigned short)((u + 0x7FFFu + ((u >> 16) & 1u)) >> 16);
}
__device__ __forceinline__ float blo(unsigned d) { return __uint_as_float(d << 16); }
__device__ __forceinline__ float bhi(unsigned d) { return __uint_as_float(d & 0xFFFF0000u); }
__device__ __forceinline__ float b2f(unsigned short v) { return __uint_as_float(((unsigned)v) << 16); }

// ---------------- K0: tiny precompute of fused weight products ----------------
__global__ void k0_precompute(const float* __restrict__ wq, const float* __restrict__ bq,
                              const float* __restrict__ wk, const float* __restrict__ bk,
                              const float* __restrict__ wv, const float* __restrict__ bv,
                              const float* __restrict__ wp, const float* __restrict__ bp,
                              float* __restrict__ ws) {
  int idx = blockIdx.x * 256 + threadIdx.x;
  const float ALPHA = 0.125f * 1.4426950408889634f;  // C^-0.5 * log2(e), folded into scores
  if (idx < 4096) {
    int cp = idx >> 6, c = idx & 63;
    float s = 0.f;
    for (int o = 0; o < 64; ++o) s += wk[o*64 + c] * wq[o*64 + cp];
    ws[WS_GX + idx] = s * ALPHA;
  } else if (idx < 8192) {
    int i = idx - 4096; int c = i >> 6, o = i & 63;
    float s = 0.f;
    for (int m = 0; m < 64; ++m) s += wp[o*64 + m] * wv[m*64 + c];
    ws[WS_CPV + i] = s;
  } else if (idx < 8256) {
    int c = idx - 8192;
    float s = 0.f;
    for (int o = 0; o < 64; ++o) s += wk[o*64 + c] * bq[o];
    ws[WS_QB + c] = s * ALPHA;
  } else if (idx < 8320) {
    int o = idx - 8256;
    float s = bp[o];
    for (int m = 0; m < 64; ++m) s += wp[o*64 + m] * bv[m];
    ws[WS_BPV + o] = s;
  }
}

// ---------------- K1: per-sample pipeline (conv1 -> GN -> attention -> conv2) ----------------
// block = 384 threads; thread = (token-slot ts = tid>>2 handling tokens {ts, ts+96},
// quarter q = tid&3 owning channels q*16..q*16+15).
// h stored BF16 in LDS: rowE(c) = 200*c + 8*(c>>4)  (8-elem = 16B skew per quarter ->
// the wave's 4 distinct b128 broadcast addresses land on 4 disjoint bank groups).
// LDS block ~29 KB -> 4-5 resident blocks/CU (vs 1 at R4's 53 KB) to hide latency.
// Residual/conv2 stay fp32: res staged fp32 in two 32-row passes aliasing the dead bf16 buf.
__launch_bounds__(384, 4)
__global__ void k1_sample(const float* __restrict__ x,
                          const float* __restrict__ w1, const float* __restrict__ b1,
                          const float* __restrict__ chw, const float* __restrict__ chb,
                          const float* __restrict__ gnw, const float* __restrict__ gnb,
                          const float* __restrict__ ch2w, const float* __restrict__ ch2b,
                          const float* __restrict__ ws, float* __restrict__ c2out) {
  __shared__ unsigned short HsB[12904];   // bf16 h: rowE(63)+200 = 12824; fp32 res alias: 32*201*2=12864
  __shared__ float redS[384];
  __shared__ float redQ[384];
  __shared__ float scS[64];
  __shared__ float shS[64];
  float* resF = reinterpret_cast<float*>(HsB);   // 32 rows x stride 201 (fp32), 2 passes

  const int tid = threadIdx.x;
  const int ts  = tid >> 2;            // token slot 0..95
  const int q   = tid & 3;             // quarter 0..3
  const int c0  = q * 16;              // my channel base
  const int t0  = ts, t1 = ts + 96;    // my two tokens
  const int myE = q * 3208;            // rowE(c0+j) = myE + 200*j
  const int b   = blockIdx.x;

  const float x0 = x[b*3+0], x1 = x[b*3+1], x2 = x[b*3+2];

  auto mk_window = [&](int t, float* hv) {
    int y = t >> 6, xx = t & 63;
    #pragma unroll
    for (int dy = 0; dy < 3; ++dy) {
      int r = y + dy - 1;
      bool rv = (r >= 0) && (r < 3);
      float xr = (r == 0) ? x0 : ((r == 1) ? x1 : x2);
      #pragma unroll
      for (int dx = 0; dx < 3; ++dx) {
        int cc = xx + dx - 1;
        bool cv = (cc >= 0) && (cc < 64);
        float w1v = cv ? w1[cc] : 0.f;
        float b1v = cv ? b1[cc] : 0.f;
        hv[dy*3+dx] = rv ? fmaf(xr, w1v, cv ? b1v : 0.f) : 0.f;
      }
    }
  };

  // ---- conv1 (1->64): fp32 compute, bf16 store ----
  {
    float hv0[9], hv1[9];
    mk_window(t0, hv0);
    mk_window(t1, hv1);
    #pragma unroll
    for (int j = 0; j < 16; ++j) {
      int c = c0 + j;
      float a0 = chb[c], a1 = a0;
      #pragma unroll
      for (int k = 0; k < 9; ++k) {
        float w = chw[c*9+k];
        a0 = fmaf(w, hv0[k], a0);
        a1 = fmaf(w, hv1[k], a1);
      }
      HsB[myE + 200*j + t0] = f2b(a0);
      HsB[myE + 200*j + t1] = f2b(a1);
    }
  }
  __syncthreads();

  // ---- instance-norm stats over the bf16-stored values (self-consistent) ----
  {
    int c = tid & 63, seg = tid >> 6;    // seg wave-uniform
    int eb = 200*c + 8*(c>>4) + seg*32;
    const unsigned* p32 = (const unsigned*)&HsB[eb];
    float s = 0.f, qq = 0.f;
    #pragma unroll
    for (int i = 0; i < 16; ++i) {
      unsigned d = p32[i];
      float f0 = blo(d), f1 = bhi(d);
      s += f0 + f1;
      qq = fmaf(f0, f0, qq); qq = fmaf(f1, f1, qq);
    }
    redS[tid] = s; redQ[tid] = qq;
  }
  __syncthreads();
  if (tid < 64) {
    float s = 0.f, qq = 0.f;
    #pragma unroll
    for (int g = 0; g < 6; ++g) { s += redS[g*64 + tid]; qq += redQ[g*64 + tid]; }
    float mu  = s * (1.f/192.f);
    float var = qq * (1.f/192.f) - mu*mu;
    float rs  = rsqrtf(var + 1e-5f);
    float sc  = gnw[tid] * rs;
    scS[tid] = sc;
    shS[tid] = gnb[tid] - mu * sc;
  }
  __syncthreads();
  // normalize in place (my 16 channels at my 2 tokens)
  #pragma unroll
  for (int j = 0; j < 16; ++j) {
    int c = c0 + j, e = myE + 200*j;
    float h0 = b2f(HsB[e + t0]);
    float h1 = b2f(HsB[e + t1]);
    HsB[e + t0] = f2b(fmaf(h0, scS[c], shS[c]));
    HsB[e + t1] = f2b(fmaf(h1, scS[c], shS[c]));
  }
  __syncthreads();

  // ---- attention ----
  const float* __restrict__ Gx  = ws + WS_GX;
  const float* __restrict__ qb  = ws + WS_QB;
  const float* __restrict__ Cpv = ws + WS_CPV;
  const float* __restrict__ bpv = ws + WS_BPV;

  // q~ for my 16 channels, both tokens
  float qt0[16], qt1[16];
  #pragma unroll
  for (int j = 0; j < 16; ++j) { qt0[j] = qb[c0+j]; qt1[j] = qt0[j]; }
  #pragma unroll 4
  for (int cp = 0; cp < 64; ++cp) {
    int eb = 200*cp + 8*(cp>>4);
    float h0 = b2f(HsB[eb + t0]);
    float h1 = b2f(HsB[eb + t1]);
    const float4* g4 = (const float4*)(Gx + cp*64 + c0);
    #pragma unroll
    for (int i = 0; i < 4; ++i) {
      float4 g = g4[i];
      qt0[4*i+0] = fmaf(g.x, h0, qt0[4*i+0]); qt1[4*i+0] = fmaf(g.x, h1, qt1[4*i+0]);
      qt0[4*i+1] = fmaf(g.y, h0, qt0[4*i+1]); qt1[4*i+1] = fmaf(g.y, h1, qt1[4*i+1]);
      qt0[4*i+2] = fmaf(g.z, h0, qt0[4*i+2]); qt1[4*i+2] = fmaf(g.z, h1, qt1[4*i+2]);
      qt0[4*i+3] = fmaf(g.w, h0, qt0[4*i+3]); qt1[4*i+3] = fmaf(g.w, h1, qt1[4*i+3]);
    }
  }

  // softmax (no max subtraction: scores O(0.05), exp2 safe) + g = attn @ h
  float ga0[16], ga1[16];
  #pragma unroll
  for (int j = 0; j < 16; ++j) { ga0[j] = 0.f; ga1[j] = 0.f; }
  float l0v = 0.f, l1v = 0.f;

  #pragma unroll 1
  for (int u0 = 0; u0 < 192; u0 += 8) {
    float s0[8], s1[8];
    #pragma unroll
    for (int k = 0; k < 8; ++k) { s0[k] = 0.f; s1[k] = 0.f; }
    #pragma unroll
    for (int j = 0; j < 16; ++j) {
      uint4 d = *(const uint4*)&HsB[myE + 200*j + u0];
      float qa = qt0[j], qc = qt1[j];
      float h0 = blo(d.x), h1 = bhi(d.x), h2 = blo(d.y), h3 = bhi(d.y);
      float h4 = blo(d.z), h5 = bhi(d.z), h6 = blo(d.w), h7 = bhi(d.w);
      s0[0]=fmaf(qa,h0,s0[0]); s0[1]=fmaf(qa,h1,s0[1]); s0[2]=fmaf(qa,h2,s0[2]); s0[3]=fmaf(qa,h3,s0[3]);
      s0[4]=fmaf(qa,h4,s0[4]); s0[5]=fmaf(qa,h5,s0[5]); s0[6]=fmaf(qa,h6,s0[6]); s0[7]=fmaf(qa,h7,s0[7]);
      s1[0]=fmaf(qc,h0,s1[0]); s1[1]=fmaf(qc,h1,s1[1]); s1[2]=fmaf(qc,h2,s1[2]); s1[3]=fmaf(qc,h3,s1[3]);
      s1[4]=fmaf(qc,h4,s1[4]); s1[5]=fmaf(qc,h5,s1[5]); s1[6]=fmaf(qc,h6,s1[6]); s1[7]=fmaf(qc,h7,s1[7]);
    }
    // complete 64-ch dots across the quad, then exp2
    #pragma unroll
    for (int k = 0; k < 8; ++k) {
      float a = s0[k]; a += __shfl_xor(a,1); a += __shfl_xor(a,2);
      float c = s1[k]; c += __shfl_xor(c,1); c += __shfl_xor(c,2);
      a = __builtin_exp2f(a);
      c = __builtin_exp2f(c);
      s0[k] = a; s1[k] = c;
      l0v += a; l1v += c;
    }
    // launder u0 so gacc re-reads aren't CSE'd (keeps h out of long-lived VGPRs)
    int u0b = u0;
    asm volatile("" : "+v"(u0b));
    #pragma unroll
    for (int j = 0; j < 16; ++j) {
      uint4 d = *(const uint4*)&HsB[myE + 200*j + u0b];
      float h0 = blo(d.x), h1 = bhi(d.x), h2 = blo(d.y), h3 = bhi(d.y);
      float h4 = blo(d.z), h5 = bhi(d.z), h6 = blo(d.w), h7 = bhi(d.w);
      float g0 = ga0[j];
      g0 = fmaf(s0[0],h0,g0); g0 = fmaf(s0[1],h1,g0); g0 = fmaf(s0[2],h2,g0); g0 = fmaf(s0[3],h3,g0);
      g0 = fmaf(s0[4],h4,g0); g0 = fmaf(s0[5],h5,g0); g0 = fmaf(s0[6],h6,g0); g0 = fmaf(s0[7],h7,g0);
      ga0[j] = g0;
      float g1 = ga1[j];
      g1 = fmaf(s1[0],h0,g1); g1 = fmaf(s1[1],h1,g1); g1 = fmaf(s1[2],h2,g1); g1 = fmaf(s1[3],h3,g1);
      g1 = fmaf(s1[4],h4,g1); g1 = fmaf(s1[5],h5,g1); g1 = fmaf(s1[6],h6,g1); g1 = fmaf(s1[7],h7,g1);
      ga1[j] = g1;
    }
  }

  // normalize g and round-trip through LDS (bf16; h content dead now)
  {
    float r0 = 1.f / l0v, r1 = 1.f / l1v;
    __syncthreads();
    #pragma unroll
    for (int j = 0; j < 16; ++j) {
      int e = myE + 200*j;
      HsB[e + t0] = f2b(ga0[j] * r0);
      HsB[e + t1] = f2b(ga1[j] * r1);
    }
  }
  __syncthreads();

  // p[c0+o] = bpv[c0+o] + sum_c Cpv[c][c0+o] * g[c]
  float keep0[16], keep1[16];
  #pragma unroll
  for (int o = 0; o < 16; ++o) { keep0[o] = bpv[c0+o]; keep1[o] = keep0[o]; }
  #pragma unroll 4
  for (int c = 0; c < 64; ++c) {
    int eb = 200*c + 8*(c>>4);
    float g0 = b2f(HsB[eb + t0]);
    float g1 = b2f(HsB[eb + t1]);
    const float4* c4 = (const float4*)(Cpv + c*64 + c0);
    #pragma unroll
    for (int i = 0; i < 4; ++i) {
      float4 cv = c4[i];
      keep0[4*i+0] = fmaf(cv.x, g0, keep0[4*i+0]); keep1[4*i+0] = fmaf(cv.x, g1, keep1[4*i+0]);
      keep0[4*i+1] = fmaf(cv.y, g0, keep0[4*i+1]); keep1[4*i+1] = fmaf(cv.y, g1, keep1[4*i+1]);
      keep0[4*i+2] = fmaf(cv.z, g0, keep0[4*i+2]); keep1[4*i+2] = fmaf(cv.z, g1, keep1[4*i+2]);
      keep0[4*i+3] = fmaf(cv.w, g0, keep0[4*i+3]); keep1[4*i+3] = fmaf(cv.w, g1, keep1[4*i+3]);
    }
  }
  __syncthreads();   // all g reads complete before resF overwrite

  // ---- residual + conv2 (64->8) in two fp32 passes over 32 channels each ----
  // resF stride 201: q-groups (8 rows) land 8 banks apart -> <=2-way (free).
  float hv0[9], hv1[9];
  mk_window(t0, hv0);
  mk_window(t1, hv1);
  float ac0[8], ac1[8];   // conv2 partials: 8 oc x {t0,t1}
  #pragma unroll
  for (int o = 0; o < 8; ++o) { ac0[o] = 0.f; ac1[o] = 0.f; }
  const int y0 = t0 >> 6, xx0 = t0 & 63;
  const int y1 = t1 >> 6, xx1 = t1 & 63;

  #pragma unroll 1
  for (int pass = 0; pass < 2; ++pass) {
    if ((q >> 1) == pass) {            // q in {2*pass, 2*pass+1} stages its 16 rows
      #pragma unroll
      for (int j = 0; j < 16; ++j) {
        int c = c0 + j;
        float a0 = chb[c], a1 = a0;
        #pragma unroll
        for (int k = 0; k < 9; ++k) {
          float w = chw[c*9+k];
          a0 = fmaf(w, hv0[k], a0);
          a1 = fmaf(w, hv1[k], a1);
        }
        int rr = (q & 1) * 16 + j;
        resF[rr*201 + t0] = a0 + keep0[j];
        resF[rr*201 + t1] = a1 + keep1[j];
      }
    }
    __syncthreads();
    // partial conv2 over the 32 staged channels; thread handles rows q*8..q*8+7
    #pragma unroll
    for (int sub = 0; sub < 8; ++sub) {
      int rr = q*8 + sub;
      int c  = pass*32 + rr;
      const float* rf = resF + rr*201;
      float win0[9], win1[9];
      #pragma unroll
      for (int dy = 0; dy < 3; ++dy) {
        int r0 = y0 + dy - 1, r1 = y1 + dy - 1;
        bool rv0 = (r0 >= 0) && (r0 < 3);
        bool rv1 = (r1 >= 0) && (r1 < 3);
        #pragma unroll
        for (int dx = 0; dx < 3; ++dx) {
          int cc0 = xx0 + dx - 1, cc1 = xx1 + dx - 1;
          bool cv0 = (cc0 >= 0) && (cc0 < 64);
          bool cv1 = (cc1 >= 0) && (cc1 < 64);
          win0[dy*3+dx] = (rv0 && cv0) ? rf[r0*64 + cc0] : 0.f;
          win1[dy*3+dx] = (rv1 && cv1) ? rf[r1*64 + cc1] : 0.f;
        }
      }
      #pragma unroll
      for (int o = 0; o < 8; ++o) {
        const float* w = ch2w + o*576 + c*9;
        float a0 = ac0[o], a1 = ac1[o];
        #pragma unroll
        for (int k = 0; k < 9; ++k) {
          float wv = w[k];
          a0 = fmaf(wv, win0[k], a0);
          a1 = fmaf(wv, win1[k], a1);
        }
        ac0[o] = a0; ac1[o] = a1;
      }
    }
    __syncthreads();   // done reading this pass's resF before next overwrite
  }

  // quad-reduce the 8-oc partials (each quad covered disjoint channel sets), write oc {2q,2q+1}
  {
    float o00 = 0.f, o01 = 0.f, o10 = 0.f, o11 = 0.f;
    #pragma unroll
    for (int o = 0; o < 8; ++o) {
      float v0 = ac0[o]; v0 += __shfl_xor(v0,1); v0 += __shfl_xor(v0,2);
      float v1 = ac1[o]; v1 += __shfl_xor(v1,1); v1 += __shfl_xor(v1,2);
      if (o == 2*q)     { o00 = v0; o10 = v1; }
      if (o == 2*q + 1) { o01 = v0; o11 = v1; }
    }
    o00 += ch2b[2*q];   o01 += ch2b[2*q+1];
    o10 += ch2b[2*q];   o11 += ch2b[2*q+1];
    c2out[b*1536 + (2*q  )*192 + t0] = o00;
    c2out[b*1536 + (2*q+1)*192 + t0] = o01;
    c2out[b*1536 + (2*q  )*192 + t1] = o10;
    c2out[b*1536 + (2*q+1)*192 + t1] = o11;
  }
}

// ---------------- K2: fc1 GEMM  z1[4096][768] = relu(c2[4096][1536] @ w2^T + b2) ----------------
__launch_bounds__(256, 4)
__global__ void k2_fc1(const float* __restrict__ A, const float* __restrict__ w2,
                       const float* __restrict__ b2, float* __restrict__ z1) {
  __shared__ float As[128 * 33];
  __shared__ float Bs[32 * 68];
  const int tid = threadIdx.x;
  const int m0 = blockIdx.x * 128;
  const int n0 = blockIdx.y * 64;
  const int tm = tid & 15, tn = tid >> 4;   // tn 0..15

  float acc[8][4];
  #pragma unroll
  for (int i = 0; i < 8; ++i)
    #pragma unroll
    for (int j = 0; j < 4; ++j) acc[i][j] = 0.f;

  for (int k0 = 0; k0 < 1536; k0 += 32) {
    #pragma unroll
    for (int i = 0; i < 4; ++i) {   // stage A 128x32
      int j = tid + i*256;
      int mm = j >> 3, k4 = (j & 7) << 2;
      float4 v = *(const float4*)&A[(m0+mm)*1536 + k0 + k4];
      As[mm*33 + k4+0] = v.x; As[mm*33 + k4+1] = v.y;
      As[mm*33 + k4+2] = v.z; As[mm*33 + k4+3] = v.w;
    }
    #pragma unroll
    for (int i = 0; i < 2; ++i) {   // stage B 64x32 transposed -> Bs[k][68]
      int j = tid + i*256;
      int nn = j >> 3, k4 = (j & 7) << 2;
      float4 v = *(const float4*)&w2[(n0+nn)*1536 + k0 + k4];
      Bs[(k4+0)*68 + nn] = v.x; Bs[(k4+1)*68 + nn] = v.y;
      Bs[(k4+2)*68 + nn] = v.z; Bs[(k4+3)*68 + nn] = v.w;
    }
    __syncthreads();
    #pragma unroll
    for (int k = 0; k < 32; ++k) {
      float a[8];
      #pragma unroll
      for (int i = 0; i < 8; ++i) a[i] = As[(tm + 16*i)*33 + k];
      float4 bv = *(const float4*)&Bs[k*68 + tn*4];
      #pragma unroll
      for (int i = 0; i < 8; ++i) {
        acc[i][0] = fmaf(a[i], bv.x, acc[i][0]);
        acc[i][1] = fmaf(a[i], bv.y, acc[i][1]);
        acc[i][2] = fmaf(a[i], bv.z, acc[i][2]);
        acc[i][3] = fmaf(a[i], bv.w, acc[i][3]);
      }
    }
    __syncthreads();
  }
  float4 bb = *(const float4*)&b2[n0 + tn*4];
  #pragma unroll
  for (int i = 0; i < 8; ++i) {
    float4 r;
    r.x = fmaxf(acc[i][0] + bb.x, 0.f);
    r.y = fmaxf(acc[i][1] + bb.y, 0.f);
    r.z = fmaxf(acc[i][2] + bb.z, 0.f);
    r.w = fmaxf(acc[i][3] + bb.w, 0.f);
    *(float4*)&z1[(m0 + tm + 16*i)*768 + n0 + tn*4] = r;
  }
}

// ---------------- K3: fc2+relu+fc3  out[b] = b4 + sum_o w4[o]*relu(b3[o] + w3[o].z1[b]) ----------------
__launch_bounds__(256, 2)
__global__ void k3_fc23(const float* __restrict__ z1, const float* __restrict__ w3,
                        const float* __restrict__ b3, const float* __restrict__ w4,
                        const float* __restrict__ b4, float* __restrict__ out) {
  __shared__ float Zs[16 * 772];
  __shared__ float Ws[32 * 68];
  __shared__ float red[256];
  const int tid = threadIdx.x;
  const int m0 = blockIdx.x * 16;
  const int tm = tid & 15, tn = tid >> 4;   // tn 0..15 -> 4 fc2 outputs each

  #pragma unroll
  for (int i = 0; i < 12; ++i) {   // stage Zs 16x768
    int j = tid + i*256;
    int mm = j / 192;
    int kq = j - mm*192;
    float4 v = *(const float4*)&z1[(m0+mm)*768 + kq*4];
    *(float4*)&Zs[mm*772 + kq*4] = v;
  }

  float a0 = 0.f, a1 = 0.f, a2 = 0.f, a3 = 0.f;
  for (int k0 = 0; k0 < 768; k0 += 32) {
    __syncthreads();
    #pragma unroll
    for (int i = 0; i < 2; ++i) {  // stage Ws[32k][68] transposed from w3[n][k]
      int j = tid + i*256;
      int nn = j >> 3, k4 = (j & 7) << 2;
      float4 v = *(const float4*)&w3[nn*768 + k0 + k4];
      Ws[(k4+0)*68 + nn] = v.x; Ws[(k4+1)*68 + nn] = v.y;
      Ws[(k4+2)*68 + nn] = v.z; Ws[(k4+3)*68 + nn] = v.w;
    }
    __syncthreads();
    #pragma unroll
    for (int k = 0; k < 32; k += 4) {
      float4 z  = *(const float4*)&Zs[tm*772 + k0 + k];
      float4 w0 = *(const float4*)&Ws[(k+0)*68 + tn*4];
      float4 w1v= *(const float4*)&Ws[(k+1)*68 + tn*4];
      float4 w2v= *(const float4*)&Ws[(k+2)*68 + tn*4];
      float4 w3v= *(const float4*)&Ws[(k+3)*68 + tn*4];
      a0 = fmaf(z.x, w0.x, a0); a1 = fmaf(z.x, w0.y, a1); a2 = fmaf(z.x, w0.z, a2); a3 = fmaf(z.x, w0.w, a3);
      a0 = fmaf(z.y, w1v.x, a0); a1 = fmaf(z.y, w1v.y, a1); a2 = fmaf(z.y, w1v.z, a2); a3 = fmaf(z.y, w1v.w, a3);
      a0 = fmaf(z.z, w2v.x, a0); a1 = fmaf(z.z, w2v.y, a1); a2 = fmaf(z.z, w2v.z, a2); a3 = fmaf(z.z, w2v.w, a3);
      a0 = fmaf(z.w, w3v.x, a0); a1 = fmaf(z.w, w3v.y, a1); a2 = fmaf(z.w, w3v.z, a2); a3 = fmaf(z.w, w3v.w, a3);
    }
  }
  float4 b3v = *(const float4*)&b3[tn*4];
  float4 w4v = *(const float4*)&w4[tn*4];
  float p = fmaxf(a0 + b3v.x, 0.f) * w4v.x
          + fmaxf(a1 + b3v.y, 0.f) * w4v.y
          + fmaxf(a2 + b3v.z, 0.f) * w4v.z
          + fmaxf(a3 + b3v.w, 0.f) * w4v.w;
  red[tid] = p;
  __syncthreads();
  if (tid < 16) {
    float s = 0.f;
    #pragma unroll
    for (int i = 0; i < 16; ++i) s += red[i*16 + tid];
    out[m0 + tid] = s + b4[0];
  }
}

extern "C" void kernel_launch(void* const* d_in, const int* in_sizes, int n_in,
                              void* d_out, int out_size, void* d_ws, size_t ws_size,
                              hipStream_t stream) {
  const float* x    = (const float*)d_in[0];
  const float* w1   = (const float*)d_in[1];
  const float* b1   = (const float*)d_in[2];
  const float* chw  = (const float*)d_in[3];
  const float* chb  = (const float*)d_in[4];
  const float* gnw  = (const float*)d_in[5];
  const float* gnb  = (const float*)d_in[6];
  const float* wq   = (const float*)d_in[7];
  const float* bq   = (const float*)d_in[8];
  const float* wk   = (const float*)d_in[9];
  const float* bk   = (const float*)d_in[10];
  const float* wv   = (const float*)d_in[11];
  const float* bv   = (const float*)d_in[12];
  const float* wp   = (const float*)d_in[13];
  const float* bp   = (const float*)d_in[14];
  const float* ch2w = (const float*)d_in[15];
  const float* ch2b = (const float*)d_in[16];
  const float* w2   = (const float*)d_in[17];
  const float* b2   = (const float*)d_in[18];
  const float* w3   = (const float*)d_in[19];
  const float* b3   = (const float*)d_in[20];
  const float* w4   = (const float*)d_in[21];
  const float* b4   = (const float*)d_in[22];
  (void)bk; (void)in_sizes; (void)n_in; (void)out_size; (void)ws_size;

  float* ws = (float*)d_ws;
  float* c2 = ws + WS_C2;
  float* z1 = ws + WS_Z1;
  float* out = (float*)d_out;

  hipLaunchKernelGGL(k0_precompute, dim3(34), dim3(256), 0, stream,
                     wq, bq, wk, bk, wv, bv, wp, bp, ws);
  hipLaunchKernelGGL(k1_sample, dim3(4096), dim3(384), 0, stream,
                     x, w1, b1, chw, chb, gnw, gnb, ch2w, ch2b, ws, c2);
  hipLaunchKernelGGL(k2_fc1, dim3(32, 12), dim3(256), 0, stream, c2, w2, b2, z1);
  hipLaunchKernelGGL(k3_fc23, dim3(256), dim3(256), 0, stream, z1, w3, b3, w4, b4, out);
}

// Round 6
// 6559.785 us; speedup vs baseline: 1.0038x; 1.0038x over previous
//
#include <hip/hip_runtime.h>

// ws layout (floats)
#define WS_GX   0                       // 4096: Gx[cp][c] = alpha*sum_o wk[o][c]*wq[o][cp]
#define WS_CPV  4096                    // 4096: Cpvx[c][o] = sum_m wp[o][m]*wv[m][c]
#define WS_QB   8192                    // 64:   alpha * Wk^T bq
#define WS_BPV  8256                    // 64:   Wp bv + bp
#define WS_C2   8448                    // 4096*1536 conv2 output (flattened fc input)
#define WS_Z1   (8448 + 4096*1536)      // 4096*768 fc1 output

// bf16 helpers: store round-to-nearest-even, load = shift/mask (1 VALU per value)
__device__ __forceinline__ unsigned short f2b(float f) {
  unsigned u = __float_as_uint(f);
  return (unsigned short)((u + 0x7FFFu + ((u >> 16) & 1u)) >> 16);
}
__device__ __forceinline__ float blo(unsigned d) { return __uint_as_float(d << 16); }
__device__ __forceinline__ float bhi(unsigned d) { return __uint_as_float(d & 0xFFFF0000u); }
__device__ __forceinline__ float b2f(unsigned short v) { return __uint_as_float(((unsigned)v) << 16); }

// ---------------- K0: tiny precompute of fused weight products ----------------
__global__ void k0_precompute(const float* __restrict__ wq, const float* __restrict__ bq,
                              const float* __restrict__ wk, const float* __restrict__ bk,
                              const float* __restrict__ wv, const float* __restrict__ bv,
                              const float* __restrict__ wp, const float* __restrict__ bp,
                              float* __restrict__ ws) {
  int idx = blockIdx.x * 256 + threadIdx.x;
  const float ALPHA = 0.125f * 1.4426950408889634f;  // C^-0.5 * log2(e), folded into scores
  if (idx < 4096) {
    int cp = idx >> 6, c = idx & 63;
    float s = 0.f;
    for (int o = 0; o < 64; ++o) s += wk[o*64 + c] * wq[o*64 + cp];
    ws[WS_GX + idx] = s * ALPHA;
  } else if (idx < 8192) {
    int i = idx - 4096; int c = i >> 6, o = i & 63;
    float s = 0.f;
    for (int m = 0; m < 64; ++m) s += wp[o*64 + m] * wv[m*64 + c];
    ws[WS_CPV + i] = s;
  } else if (idx < 8256) {
    int c = idx - 8192;
    float s = 0.f;
    for (int o = 0; o < 64; ++o) s += wk[o*64 + c] * bq[o];
    ws[WS_QB + c] = s * ALPHA;
  } else if (idx < 8320) {
    int o = idx - 8256;
    float s = bp[o];
    for (int m = 0; m < 64; ++m) s += wp[o*64 + m] * bv[m];
    ws[WS_BPV + o] = s;
  }
}

// ---------------- K1: per-sample pipeline (conv1 -> GN -> attention -> conv2) ----------------
// block = 384 threads; thread = (token-slot ts = tid>>2 handling tokens {ts, ts+96},
// quarter q = tid&3 owning channels q*16..q*16+15).
// h stored BF16 in LDS: rowE(c) = 200*c + 8*(c>>4)  (16B skew per quarter -> the wave's 4
// distinct b128 broadcast addresses land on 4 disjoint bank groups).
// __launch_bounds__(384,3): (384,4) made the backend clamp VGPR to 64 -> 12 GB scratch
// spill (R5). At 3 waves/EU the cap is ~170; live set ~100 fits (R4 compiled at 76).
__launch_bounds__(384, 3)
__global__ void k1_sample(const float* __restrict__ x,
                          const float* __restrict__ w1, const float* __restrict__ b1,
                          const float* __restrict__ chw, const float* __restrict__ chb,
                          const float* __restrict__ gnw, const float* __restrict__ gnb,
                          const float* __restrict__ ch2w, const float* __restrict__ ch2b,
                          const float* __restrict__ ws, float* __restrict__ c2out) {
  __shared__ unsigned short HsB[12904];   // bf16 h; fp32 res alias: 32*201*2=12864
  __shared__ float redS[384];
  __shared__ float redQ[384];
  __shared__ float scS[64];
  __shared__ float shS[64];
  float* resF = reinterpret_cast<float*>(HsB);   // 32 rows x stride 201 (fp32), 2 passes

  const int tid = threadIdx.x;
  const int ts  = tid >> 2;            // token slot 0..95
  const int q   = tid & 3;             // quarter 0..3
  const int c0  = q * 16;              // my channel base
  const int t0  = ts, t1 = ts + 96;    // my two tokens
  const int myE = q * 3208;            // rowE(c0+j) = myE + 200*j
  const int b   = blockIdx.x;

  const float x0 = x[b*3+0], x1 = x[b*3+1], x2 = x[b*3+2];

  auto mk_window = [&](int t, float* hv) {
    int y = t >> 6, xx = t & 63;
    #pragma unroll
    for (int dy = 0; dy < 3; ++dy) {
      int r = y + dy - 1;
      bool rv = (r >= 0) && (r < 3);
      float xr = (r == 0) ? x0 : ((r == 1) ? x1 : x2);
      #pragma unroll
      for (int dx = 0; dx < 3; ++dx) {
        int cc = xx + dx - 1;
        bool cv = (cc >= 0) && (cc < 64);
        float w1v = cv ? w1[cc] : 0.f;
        float b1v = cv ? b1[cc] : 0.f;
        hv[dy*3+dx] = rv ? fmaf(xr, w1v, cv ? b1v : 0.f) : 0.f;
      }
    }
  };

  // ---- conv1 (1->64): fp32 compute, bf16 store ----
  {
    float hv0[9], hv1[9];
    mk_window(t0, hv0);
    mk_window(t1, hv1);
    #pragma unroll
    for (int j = 0; j < 16; ++j) {
      int c = c0 + j;
      float a0 = chb[c], a1 = a0;
      #pragma unroll
      for (int k = 0; k < 9; ++k) {
        float w = chw[c*9+k];
        a0 = fmaf(w, hv0[k], a0);
        a1 = fmaf(w, hv1[k], a1);
      }
      HsB[myE + 200*j + t0] = f2b(a0);
      HsB[myE + 200*j + t1] = f2b(a1);
    }
  }
  __syncthreads();

  // ---- instance-norm stats over the bf16-stored values (self-consistent) ----
  {
    int c = tid & 63, seg = tid >> 6;    // seg wave-uniform
    int eb = 200*c + 8*(c>>4) + seg*32;
    const unsigned* p32 = (const unsigned*)&HsB[eb];
    float s = 0.f, qq = 0.f;
    #pragma unroll
    for (int i = 0; i < 16; ++i) {
      unsigned d = p32[i];
      float f0 = blo(d), f1 = bhi(d);
      s += f0 + f1;
      qq = fmaf(f0, f0, qq); qq = fmaf(f1, f1, qq);
    }
    redS[tid] = s; redQ[tid] = qq;
  }
  __syncthreads();
  if (tid < 64) {
    float s = 0.f, qq = 0.f;
    #pragma unroll
    for (int g = 0; g < 6; ++g) { s += redS[g*64 + tid]; qq += redQ[g*64 + tid]; }
    float mu  = s * (1.f/192.f);
    float var = qq * (1.f/192.f) - mu*mu;
    float rs  = rsqrtf(var + 1e-5f);
    float sc  = gnw[tid] * rs;
    scS[tid] = sc;
    shS[tid] = gnb[tid] - mu * sc;
  }
  __syncthreads();
  // normalize in place (my 16 channels at my 2 tokens)
  #pragma unroll
  for (int j = 0; j < 16; ++j) {
    int c = c0 + j, e = myE + 200*j;
    float h0 = b2f(HsB[e + t0]);
    float h1 = b2f(HsB[e + t1]);
    HsB[e + t0] = f2b(fmaf(h0, scS[c], shS[c]));
    HsB[e + t1] = f2b(fmaf(h1, scS[c], shS[c]));
  }
  __syncthreads();

  // ---- attention ----
  const float* __restrict__ Gx  = ws + WS_GX;
  const float* __restrict__ qb  = ws + WS_QB;
  const float* __restrict__ Cpv = ws + WS_CPV;
  const float* __restrict__ bpv = ws + WS_BPV;

  // q~ for my 16 channels, both tokens
  float qt0[16], qt1[16];
  #pragma unroll
  for (int j = 0; j < 16; ++j) { qt0[j] = qb[c0+j]; qt1[j] = qt0[j]; }
  #pragma unroll 4
  for (int cp = 0; cp < 64; ++cp) {
    int eb = 200*cp + 8*(cp>>4);
    float h0 = b2f(HsB[eb + t0]);
    float h1 = b2f(HsB[eb + t1]);
    const float4* g4 = (const float4*)(Gx + cp*64 + c0);
    #pragma unroll
    for (int i = 0; i < 4; ++i) {
      float4 g = g4[i];
      qt0[4*i+0] = fmaf(g.x, h0, qt0[4*i+0]); qt1[4*i+0] = fmaf(g.x, h1, qt1[4*i+0]);
      qt0[4*i+1] = fmaf(g.y, h0, qt0[4*i+1]); qt1[4*i+1] = fmaf(g.y, h1, qt1[4*i+1]);
      qt0[4*i+2] = fmaf(g.z, h0, qt0[4*i+2]); qt1[4*i+2] = fmaf(g.z, h1, qt1[4*i+2]);
      qt0[4*i+3] = fmaf(g.w, h0, qt0[4*i+3]); qt1[4*i+3] = fmaf(g.w, h1, qt1[4*i+3]);
    }
  }

  // softmax (no max subtraction: scores O(0.05), exp2 safe) + g = attn @ h
  float ga0[16], ga1[16];
  #pragma unroll
  for (int j = 0; j < 16; ++j) { ga0[j] = 0.f; ga1[j] = 0.f; }
  float l0v = 0.f, l1v = 0.f;

  #pragma unroll 1
  for (int u0 = 0; u0 < 192; u0 += 8) {
    float s0[8], s1[8];
    #pragma unroll
    for (int k = 0; k < 8; ++k) { s0[k] = 0.f; s1[k] = 0.f; }
    #pragma unroll
    for (int j = 0; j < 16; ++j) {
      uint4 d = *(const uint4*)&HsB[myE + 200*j + u0];
      float qa = qt0[j], qc = qt1[j];
      float h0 = blo(d.x), h1 = bhi(d.x), h2 = blo(d.y), h3 = bhi(d.y);
      float h4 = blo(d.z), h5 = bhi(d.z), h6 = blo(d.w), h7 = bhi(d.w);
      s0[0]=fmaf(qa,h0,s0[0]); s0[1]=fmaf(qa,h1,s0[1]); s0[2]=fmaf(qa,h2,s0[2]); s0[3]=fmaf(qa,h3,s0[3]);
      s0[4]=fmaf(qa,h4,s0[4]); s0[5]=fmaf(qa,h5,s0[5]); s0[6]=fmaf(qa,h6,s0[6]); s0[7]=fmaf(qa,h7,s0[7]);
      s1[0]=fmaf(qc,h0,s1[0]); s1[1]=fmaf(qc,h1,s1[1]); s1[2]=fmaf(qc,h2,s1[2]); s1[3]=fmaf(qc,h3,s1[3]);
      s1[4]=fmaf(qc,h4,s1[4]); s1[5]=fmaf(qc,h5,s1[5]); s1[6]=fmaf(qc,h6,s1[6]); s1[7]=fmaf(qc,h7,s1[7]);
    }
    // complete 64-ch dots across the quad, then exp2
    #pragma unroll
    for (int k = 0; k < 8; ++k) {
      float a = s0[k]; a += __shfl_xor(a,1); a += __shfl_xor(a,2);
      float c = s1[k]; c += __shfl_xor(c,1); c += __shfl_xor(c,2);
      a = __builtin_exp2f(a);
      c = __builtin_exp2f(c);
      s0[k] = a; s1[k] = c;
      l0v += a; l1v += c;
    }
    // launder u0 so gacc re-reads aren't CSE'd (keeps h out of long-lived VGPRs)
    int u0b = u0;
    asm volatile("" : "+v"(u0b));
    #pragma unroll
    for (int j = 0; j < 16; ++j) {
      uint4 d = *(const uint4*)&HsB[myE + 200*j + u0b];
      float h0 = blo(d.x), h1 = bhi(d.x), h2 = blo(d.y), h3 = bhi(d.y);
      float h4 = blo(d.z), h5 = bhi(d.z), h6 = blo(d.w), h7 = bhi(d.w);
      float g0 = ga0[j];
      g0 = fmaf(s0[0],h0,g0); g0 = fmaf(s0[1],h1,g0); g0 = fmaf(s0[2],h2,g0); g0 = fmaf(s0[3],h3,g0);
      g0 = fmaf(s0[4],h4,g0); g0 = fmaf(s0[5],h5,g0); g0 = fmaf(s0[6],h6,g0); g0 = fmaf(s0[7],h7,g0);
      ga0[j] = g0;
      float g1 = ga1[j];
      g1 = fmaf(s1[0],h0,g1); g1 = fmaf(s1[1],h1,g1); g1 = fmaf(s1[2],h2,g1); g1 = fmaf(s1[3],h3,g1);
      g1 = fmaf(s1[4],h4,g1); g1 = fmaf(s1[5],h5,g1); g1 = fmaf(s1[6],h6,g1); g1 = fmaf(s1[7],h7,g1);
      ga1[j] = g1;
    }
  }

  // normalize g and round-trip through LDS (bf16; h content dead now)
  {
    float r0 = 1.f / l0v, r1 = 1.f / l1v;
    __syncthreads();
    #pragma unroll
    for (int j = 0; j < 16; ++j) {
      int e = myE + 200*j;
      HsB[e + t0] = f2b(ga0[j] * r0);
      HsB[e + t1] = f2b(ga1[j] * r1);
    }
  }
  __syncthreads();

  // p[c0+o] = bpv[c0+o] + sum_c Cpv[c][c0+o] * g[c]
  float keep0[16], keep1[16];
  #pragma unroll
  for (int o = 0; o < 16; ++o) { keep0[o] = bpv[c0+o]; keep1[o] = keep0[o]; }
  #pragma unroll 4
  for (int c = 0; c < 64; ++c) {
    int eb = 200*c + 8*(c>>4);
    float g0 = b2f(HsB[eb + t0]);
    float g1 = b2f(HsB[eb + t1]);
    const float4* c4 = (const float4*)(Cpv + c*64 + c0);
    #pragma unroll
    for (int i = 0; i < 4; ++i) {
      float4 cv = c4[i];
      keep0[4*i+0] = fmaf(cv.x, g0, keep0[4*i+0]); keep1[4*i+0] = fmaf(cv.x, g1, keep1[4*i+0]);
      keep0[4*i+1] = fmaf(cv.y, g0, keep0[4*i+1]); keep1[4*i+1] = fmaf(cv.y, g1, keep1[4*i+1]);
      keep0[4*i+2] = fmaf(cv.z, g0, keep0[4*i+2]); keep1[4*i+2] = fmaf(cv.z, g1, keep1[4*i+2]);
      keep0[4*i+3] = fmaf(cv.w, g0, keep0[4*i+3]); keep1[4*i+3] = fmaf(cv.w, g1, keep1[4*i+3]);
    }
  }
  __syncthreads();   // all g reads complete before resF overwrite

  // ---- residual + conv2 (64->8) in two fp32 passes over 32 channels each ----
  // resF stride 201: q-groups (8 rows) land 8 banks apart -> <=2-way (free).
  float hv0[9], hv1[9];
  mk_window(t0, hv0);
  mk_window(t1, hv1);
  float ac0[8], ac1[8];   // conv2 partials: 8 oc x {t0,t1}
  #pragma unroll
  for (int o = 0; o < 8; ++o) { ac0[o] = 0.f; ac1[o] = 0.f; }
  const int y0 = t0 >> 6, xx0 = t0 & 63;
  const int y1 = t1 >> 6, xx1 = t1 & 63;

  #pragma unroll 1
  for (int pass = 0; pass < 2; ++pass) {
    if ((q >> 1) == pass) {            // q in {2*pass, 2*pass+1} stages its 16 rows
      #pragma unroll
      for (int j = 0; j < 16; ++j) {
        int c = c0 + j;
        float a0 = chb[c], a1 = a0;
        #pragma unroll
        for (int k = 0; k < 9; ++k) {
          float w = chw[c*9+k];
          a0 = fmaf(w, hv0[k], a0);
          a1 = fmaf(w, hv1[k], a1);
        }
        int rr = (q & 1) * 16 + j;
        resF[rr*201 + t0] = a0 + keep0[j];
        resF[rr*201 + t1] = a1 + keep1[j];
      }
    }
    __syncthreads();
    // partial conv2 over the 32 staged channels; thread handles rows q*8..q*8+7
    #pragma unroll
    for (int sub = 0; sub < 8; ++sub) {
      int rr = q*8 + sub;
      int c  = pass*32 + rr;
      const float* rf = resF + rr*201;
      float win0[9], win1[9];
      #pragma unroll
      for (int dy = 0; dy < 3; ++dy) {
        int r0 = y0 + dy - 1, r1 = y1 + dy - 1;
        bool rv0 = (r0 >= 0) && (r0 < 3);
        bool rv1 = (r1 >= 0) && (r1 < 3);
        #pragma unroll
        for (int dx = 0; dx < 3; ++dx) {
          int cc0 = xx0 + dx - 1, cc1 = xx1 + dx - 1;
          bool cv0 = (cc0 >= 0) && (cc0 < 64);
          bool cv1 = (cc1 >= 0) && (cc1 < 64);
          win0[dy*3+dx] = (rv0 && cv0) ? rf[r0*64 + cc0] : 0.f;
          win1[dy*3+dx] = (rv1 && cv1) ? rf[r1*64 + cc1] : 0.f;
        }
      }
      #pragma unroll
      for (int o = 0; o < 8; ++o) {
        const float* w = ch2w + o*576 + c*9;
        float a0 = ac0[o], a1 = ac1[o];
        #pragma unroll
        for (int k = 0; k < 9; ++k) {
          float wv = w[k];
          a0 = fmaf(wv, win0[k], a0);
          a1 = fmaf(wv, win1[k], a1);
        }
        ac0[o] = a0; ac1[o] = a1;
      }
    }
    __syncthreads();   // done reading this pass's resF before next overwrite
  }

  // quad-reduce the 8-oc partials, write oc {2q,2q+1}
  {
    float o00 = 0.f, o01 = 0.f, o10 = 0.f, o11 = 0.f;
    #pragma unroll
    for (int o = 0; o < 8; ++o) {
      float v0 = ac0[o]; v0 += __shfl_xor(v0,1); v0 += __shfl_xor(v0,2);
      float v1 = ac1[o]; v1 += __shfl_xor(v1,1); v1 += __shfl_xor(v1,2);
      if (o == 2*q)     { o00 = v0; o10 = v1; }
      if (o == 2*q + 1) { o01 = v0; o11 = v1; }
    }
    o00 += ch2b[2*q];   o01 += ch2b[2*q+1];
    o10 += ch2b[2*q];   o11 += ch2b[2*q+1];
    c2out[b*1536 + (2*q  )*192 + t0] = o00;
    c2out[b*1536 + (2*q+1)*192 + t0] = o01;
    c2out[b*1536 + (2*q  )*192 + t1] = o10;
    c2out[b*1536 + (2*q+1)*192 + t1] = o11;
  }
}

// ---------------- K2: fc1 GEMM  z1[4096][768] = relu(c2[4096][1536] @ w2^T + b2) ----------------
__launch_bounds__(256, 4)
__global__ void k2_fc1(const float* __restrict__ A, const float* __restrict__ w2,
                       const float* __restrict__ b2, float* __restrict__ z1) {
  __shared__ float As[128 * 33];
  __shared__ float Bs[32 * 68];
  const int tid = threadIdx.x;
  const int m0 = blockIdx.x * 128;
  const int n0 = blockIdx.y * 64;
  const int tm = tid & 15, tn = tid >> 4;   // tn 0..15

  float acc[8][4];
  #pragma unroll
  for (int i = 0; i < 8; ++i)
    #pragma unroll
    for (int j = 0; j < 4; ++j) acc[i][j] = 0.f;

  for (int k0 = 0; k0 < 1536; k0 += 32) {
    #pragma unroll
    for (int i = 0; i < 4; ++i) {   // stage A 128x32
      int j = tid + i*256;
      int mm = j >> 3, k4 = (j & 7) << 2;
      float4 v = *(const float4*)&A[(m0+mm)*1536 + k0 + k4];
      As[mm*33 + k4+0] = v.x; As[mm*33 + k4+1] = v.y;
      As[mm*33 + k4+2] = v.z; As[mm*33 + k4+3] = v.w;
    }
    #pragma unroll
    for (int i = 0; i < 2; ++i) {   // stage B 64x32 transposed -> Bs[k][68]
      int j = tid + i*256;
      int nn = j >> 3, k4 = (j & 7) << 2;
      float4 v = *(const float4*)&w2[(n0+nn)*1536 + k0 + k4];
      Bs[(k4+0)*68 + nn] = v.x; Bs[(k4+1)*68 + nn] = v.y;
      Bs[(k4+2)*68 + nn] = v.z; Bs[(k4+3)*68 + nn] = v.w;
    }
    __syncthreads();
    #pragma unroll
    for (int k = 0; k < 32; ++k) {
      float a[8];
      #pragma unroll
      for (int i = 0; i < 8; ++i) a[i] = As[(tm + 16*i)*33 + k];
      float4 bv = *(const float4*)&Bs[k*68 + tn*4];
      #pragma unroll
      for (int i = 0; i < 8; ++i) {
        acc[i][0] = fmaf(a[i], bv.x, acc[i][0]);
        acc[i][1] = fmaf(a[i], bv.y, acc[i][1]);
        acc[i][2] = fmaf(a[i], bv.z, acc[i][2]);
        acc[i][3] = fmaf(a[i], bv.w, acc[i][3]);
      }
    }
    __syncthreads();
  }
  float4 bb = *(const float4*)&b2[n0 + tn*4];
  #pragma unroll
  for (int i = 0; i < 8; ++i) {
    float4 r;
    r.x = fmaxf(acc[i][0] + bb.x, 0.f);
    r.y = fmaxf(acc[i][1] + bb.y, 0.f);
    r.z = fmaxf(acc[i][2] + bb.z, 0.f);
    r.w = fmaxf(acc[i][3] + bb.w, 0.f);
    *(float4*)&z1[(m0 + tm + 16*i)*768 + n0 + tn*4] = r;
  }
}

// ---------------- K3: fc2+relu+fc3  out[b] = b4 + sum_o w4[o]*relu(b3[o] + w3[o].z1[b]) ----------------
__launch_bounds__(256, 2)
__global__ void k3_fc23(const float* __restrict__ z1, const float* __restrict__ w3,
                        const float* __restrict__ b3, const float* __restrict__ w4,
                        const float* __restrict__ b4, float* __restrict__ out) {
  __shared__ float Zs[16 * 772];
  __shared__ float Ws[32 * 68];
  __shared__ float red[256];
  const int tid = threadIdx.x;
  const int m0 = blockIdx.x * 16;
  const int tm = tid & 15, tn = tid >> 4;   // tn 0..15 -> 4 fc2 outputs each

  #pragma unroll
  for (int i = 0; i < 12; ++i) {   // stage Zs 16x768
    int j = tid + i*256;
    int mm = j / 192;
    int kq = j - mm*192;
    float4 v = *(const float4*)&z1[(m0+mm)*768 + kq*4];
    *(float4*)&Zs[mm*772 + kq*4] = v;
  }

  float a0 = 0.f, a1 = 0.f, a2 = 0.f, a3 = 0.f;
  for (int k0 = 0; k0 < 768; k0 += 32) {
    __syncthreads();
    #pragma unroll
    for (int i = 0; i < 2; ++i) {  // stage Ws[32k][68] transposed from w3[n][k]
      int j = tid + i*256;
      int nn = j >> 3, k4 = (j & 7) << 2;
      float4 v = *(const float4*)&w3[nn*768 + k0 + k4];
      Ws[(k4+0)*68 + nn] = v.x; Ws[(k4+1)*68 + nn] = v.y;
      Ws[(k4+2)*68 + nn] = v.z; Ws[(k4+3)*68 + nn] = v.w;
    }
    __syncthreads();
    #pragma unroll
    for (int k = 0; k < 32; k += 4) {
      float4 z  = *(const float4*)&Zs[tm*772 + k0 + k];
      float4 w0 = *(const float4*)&Ws[(k+0)*68 + tn*4];
      float4 w1v= *(const float4*)&Ws[(k+1)*68 + tn*4];
      float4 w2v= *(const float4*)&Ws[(k+2)*68 + tn*4];
      float4 w3v= *(const float4*)&Ws[(k+3)*68 + tn*4];
      a0 = fmaf(z.x, w0.x, a0); a1 = fmaf(z.x, w0.y, a1); a2 = fmaf(z.x, w0.z, a2); a3 = fmaf(z.x, w0.w, a3);
      a0 = fmaf(z.y, w1v.x, a0); a1 = fmaf(z.y, w1v.y, a1); a2 = fmaf(z.y, w1v.z, a2); a3 = fmaf(z.y, w1v.w, a3);
      a0 = fmaf(z.z, w2v.x, a0); a1 = fmaf(z.z, w2v.y, a1); a2 = fmaf(z.z, w2v.z, a2); a3 = fmaf(z.z, w2v.w, a3);
      a0 = fmaf(z.w, w3v.x, a0); a1 = fmaf(z.w, w3v.y, a1); a2 = fmaf(z.w, w3v.z, a2); a3 = fmaf(z.w, w3v.w, a3);
    }
  }
  float4 b3v = *(const float4*)&b3[tn*4];
  float4 w4v = *(const float4*)&w4[tn*4];
  float p = fmaxf(a0 + b3v.x, 0.f) * w4v.x
          + fmaxf(a1 + b3v.y, 0.f) * w4v.y
          + fmaxf(a2 + b3v.z, 0.f) * w4v.z
          + fmaxf(a3 + b3v.w, 0.f) * w4v.w;
  red[tid] = p;
  __syncthreads();
  if (tid < 16) {
    float s = 0.f;
    #pragma unroll
    for (int i = 0; i < 16; ++i) s += red[i*16 + tid];
    out[m0 + tid] = s + b4[0];
  }
}

extern "C" void kernel_launch(void* const* d_in, const int* in_sizes, int n_in,
                              void* d_out, int out_size, void* d_ws, size_t ws_size,
                              hipStream_t stream) {
  const float* x    = (const float*)d_in[0];
  const float* w1   = (const float*)d_in[1];
  const float* b1   = (const float*)d_in[2];
  const float* chw  = (const float*)d_in[3];
  const float* chb  = (const float*)d_in[4];
  const float* gnw  = (const float*)d_in[5];
  const float* gnb  = (const float*)d_in[6];
  const float* wq   = (const float*)d_in[7];
  const float* bq   = (const float*)d_in[8];
  const float* wk   = (const float*)d_in[9];
  const float* bk   = (const float*)d_in[10];
  const float* wv   = (const float*)d_in[11];
  const float* bv   = (const float*)d_in[12];
  const float* wp   = (const float*)d_in[13];
  const float* bp   = (const float*)d_in[14];
  const float* ch2w = (const float*)d_in[15];
  const float* ch2b = (const float*)d_in[16];
  const float* w2   = (const float*)d_in[17];
  const float* b2   = (const float*)d_in[18];
  const float* w3   = (const float*)d_in[19];
  const float* b3   = (const float*)d_in[20];
  const float* w4   = (const float*)d_in[21];
  const float* b4   = (const float*)d_in[22];
  (void)bk; (void)in_sizes; (void)n_in; (void)out_size; (void)ws_size;

  float* ws = (float*)d_ws;
  float* c2 = ws + WS_C2;
  float* z1 = ws + WS_Z1;
  float* out = (float*)d_out;

  hipLaunchKernelGGL(k0_precompute, dim3(34), dim3(256), 0, stream,
                     wq, bq, wk, bk, wv, bv, wp, bp, ws);
  hipLaunchKernelGGL(k1_sample, dim3(4096), dim3(384), 0, stream,
                     x, w1, b1, chw, chb, gnw, gnb, ch2w, ch2b, ws, c2);
  hipLaunchKernelGGL(k2_fc1, dim3(32, 12), dim3(256), 0, stream, c2, w2, b2, z1);
  hipLaunchKernelGGL(k3_fc23, dim3(256), dim3(256), 0, stream, z1, w3, b3, w4, b4, out);
}